// Round 7
// baseline (94.036 us; speedup 1.0000x reference)
//
#include <hip/hip_runtime.h>

#define NN 2048
#define AD 64
#define HH 8
#define DD 512
#define NEG 0.2f

typedef float f32x4 __attribute__((ext_vector_type(4)));
typedef _Float16 half8 __attribute__((ext_vector_type(8)));
typedef _Float16 half2v __attribute__((ext_vector_type(2)));
typedef unsigned short u16;
typedef unsigned int u32;
typedef u16 u16x8 __attribute__((ext_vector_type(8)));

// ---------------------------------------------------------------------------
// Kernel 1: Q = X@Qw + Qb, K = X@Kw + Kb, VtH = f16(X@Vw + Vb)^T
// plus grid-stride tail: E8[i][j] = edges<0 ? 8 : edges  (u8 k-code)
// grid 384 = 3 mats x (32 row-groups x 4 col-groups), block 256
// ---------------------------------------------------------------------------
__global__ __launch_bounds__(256) void qkv_kernel(
    const float* __restrict__ X,
    const float* __restrict__ Qw, const float* __restrict__ Qb,
    const float* __restrict__ Kw, const float* __restrict__ Kb,
    const float* __restrict__ Vw, const float* __restrict__ Vb,
    const int* __restrict__ E, unsigned char* __restrict__ E8,
    float* __restrict__ Q, float* __restrict__ K, u16* __restrict__ VtH) {
  __shared__ float Xs[64][68];
  int t = threadIdx.x;
  int b = blockIdx.x;
  int m = b >> 7;           // 0:Q 1:K 2:V
  int tile = b & 127;
  int r0 = (tile >> 2) * 64;
  int d0 = (tile & 3) * 128;
  const float* W  = (m == 0) ? Qw : (m == 1) ? Kw : Vw;
  const float* Bv = (m == 0) ? Qb : (m == 1) ? Kb : Vb;

  for (int idx = t; idx < 64 * 64; idx += 256) {
    int r = idx >> 6, c = idx & 63;
    Xs[r][c] = X[(size_t)(r0 + r) * AD + c];
  }
  __syncthreads();

  int tr = t >> 5;
  int td = t & 31;
  int d = d0 + td * 4;
  float4 bias = *(const float4*)&Bv[d];
  float4 acc[8];
#pragma unroll
  for (int i = 0; i < 8; ++i) acc[i] = bias;
  for (int c = 0; c < 64; ++c) {
    float4 w = *(const float4*)&W[c * DD + d];
#pragma unroll
    for (int i = 0; i < 8; ++i) {
      float x = Xs[tr * 8 + i][c];
      acc[i].x += x * w.x; acc[i].y += x * w.y;
      acc[i].z += x * w.z; acc[i].w += x * w.w;
    }
  }
  if (m == 2) {
#pragma unroll
    for (int c = 0; c < 4; ++c) {
      u16x8 o;
#pragma unroll
      for (int i = 0; i < 8; ++i) {
        float fv = (c == 0) ? acc[i].x : (c == 1) ? acc[i].y
                 : (c == 2) ? acc[i].z : acc[i].w;
        _Float16 hf = (_Float16)fv;
        o[i] = __builtin_bit_cast(u16, hf);
      }
      *(u16x8*)&VtH[(size_t)(d + c) * NN + r0 + tr * 8] = o;
    }
  } else {
    float* O = (m == 0) ? Q : K;
#pragma unroll
    for (int i = 0; i < 8; ++i) {
      *(float4*)&O[(size_t)(r0 + tr * 8 + i) * DD + d] = acc[i];
    }
  }
  // E8 conversion tail (grid-stride over int4 quads)
  const int nquad = NN * NN / 4;
  for (int idx = b * 256 + t; idx < nquad; idx += 384 * 256) {
    int4 v = ((const int4*)E)[idx];
    uchar4 o;
    o.x = (unsigned char)(v.x < 0 ? 8 : (v.x & 7));
    o.y = (unsigned char)(v.y < 0 ? 8 : (v.y & 7));
    o.z = (unsigned char)(v.z < 0 ? 8 : (v.z & 7));
    o.w = (unsigned char)(v.w < 0 ? 8 : (v.w & 7));
    ((uchar4*)E8)[idx] = o;
  }
}

// ---------------------------------------------------------------------------
// Kernel 2: per-head packed product tables.
// TS1H[h][row][k] = u32 packed ( f16(exp(S1)*0.25), f16(exp(0.2*S1)*0.25) )
// TS2H likewise from S2. grid 512 (4 rows each), block 256.
// ---------------------------------------------------------------------------
__global__ __launch_bounds__(256) void s12_kernel(
    const float* __restrict__ Q, const float* __restrict__ K,
    const float* __restrict__ A,
    u32* __restrict__ TS1H, u32* __restrict__ TS2H) {
  __shared__ float Qs[4][512];
  __shared__ float Ks[4][512];
  __shared__ float red1[4][4][64];
  __shared__ float red2[4][4][64];
  int t = threadIdx.x;
  int r0 = blockIdx.x * 4;
  for (int idx = t; idx < 4 * 128; idx += 256) {
    int r = idx >> 7, dd = (idx & 127) * 4;
    *(float4*)&Qs[r][dd] = *(const float4*)&Q[(size_t)(r0 + r) * DD + dd];
    *(float4*)&Ks[r][dd] = *(const float4*)&K[(size_t)(r0 + r) * DD + dd];
  }
  __syncthreads();
  int kh = t & 63;
  int dg = t >> 6;
  int k = kh >> 3, h = kh & 7;
  float as1[4], as2[4];
#pragma unroll
  for (int i = 0; i < 4; ++i) { as1[i] = 0.f; as2[i] = 0.f; }
  const float* A1 = A + (size_t)k * 1024 * 8 + h;
  const float* A2 = A1 + 512 * 8;
  for (int dq = 0; dq < 32; ++dq) {
    int dd = dg * 128 + dq * 4;
    float a10 = A1[(dd + 0) * 8], a11 = A1[(dd + 1) * 8],
          a12 = A1[(dd + 2) * 8], a13 = A1[(dd + 3) * 8];
    float a20 = A2[(dd + 0) * 8], a21 = A2[(dd + 1) * 8],
          a22 = A2[(dd + 2) * 8], a23 = A2[(dd + 3) * 8];
#pragma unroll
    for (int i = 0; i < 4; ++i) {
      float4 q  = *(const float4*)&Qs[i][dd];
      float4 kk = *(const float4*)&Ks[i][dd];
      as1[i] += q.x  * a10 + q.y  * a11 + q.z  * a12 + q.w  * a13;
      as2[i] += kk.x * a20 + kk.y * a21 + kk.z * a22 + kk.w * a23;
    }
  }
#pragma unroll
  for (int i = 0; i < 4; ++i) {
    red1[dg][i][kh] = as1[i];
    red2[dg][i][kh] = as2[i];
  }
  __syncthreads();
  {
    int i = t >> 6, kk2 = t & 63;
    float v1 = red1[0][i][kk2] + red1[1][i][kk2] + red1[2][i][kk2] + red1[3][i][kk2];
    float v2 = red2[0][i][kk2] + red2[1][i][kk2] + red2[2][i][kk2] + red2[3][i][kk2];
    int kq = kk2 >> 3, hh = kk2 & 7;
    int row = r0 + i;
    _Float16 p1 = (_Float16)(__expf(v1) * 0.25f);
    _Float16 n1 = (_Float16)(__expf(NEG * v1) * 0.25f);
    _Float16 p2 = (_Float16)(__expf(v2) * 0.25f);
    _Float16 n2 = (_Float16)(__expf(NEG * v2) * 0.25f);
    u32 w1 = (u32)__builtin_bit_cast(u16, p1) | ((u32)__builtin_bit_cast(u16, n1) << 16);
    u32 w2 = (u32)__builtin_bit_cast(u16, p2) | ((u32)__builtin_bit_cast(u16, n2) << 16);
    TS1H[((size_t)hh * NN + row) * 8 + kq] = w1;
    TS2H[((size_t)hh * NN + row) * 8 + kq] = w2;
  }
}

// ---------------------------------------------------------------------------
// Kernel 3: MFMA attention — ZERO barriers; every wave an independent stream.
// grid 1024 = 128 i-tiles (16 rows) x 8 j-chunks (256 j). block 512 = 8 waves.
// Wave w = head w, fully self-contained:
//   - stages its own TS1H/TS2H [w] slices into wave-private LDS (pad-9,
//     conflict-free); double-buffers the 64-j S2 slice; E8 double-buffered
//     in regs; bfrag issued before scoring (T14).
//   - per score (lane computes its OWN A-fragment element): 1 byte k-code,
//     2 ds_read_b32, v_pk_mul_f16, max(lo,hi), cndmask(invalid->1/16).
//   - 8 numerator MFMAs + 2 ones-MFMAs (exact f32 denominator).
// LDS 41.5 KB/block, no __syncthreads anywhere.
// ---------------------------------------------------------------------------
__global__ __launch_bounds__(512, 4) void attn_mfma_kernel(
    const unsigned char* __restrict__ E8,
    const u32* __restrict__ TS1H, const u32* __restrict__ TS2H,
    const u16* __restrict__ VtH,
    float* __restrict__ PART, float* __restrict__ LPART) {
  __shared__ u32 ldsbuf[8 * 16 * 9 + 8 * 2 * 64 * 9];   // s1h | s2h
  int t = threadIdx.x;
  int w = t >> 6, lane = t & 63;
  int li = lane & 15, q = lane >> 4;
  int it = blockIdx.x >> 3, ch = blockIdx.x & 7;
  int i0 = it * 16, jch = ch * 256;

  u32* s1h = ldsbuf + w * (16 * 9);
  u32* s2h = ldsbuf + 8 * 16 * 9 + w * (2 * 64 * 9);

  // stage s1h (wave-local): lane -> row = lane>>2, kpair = (lane&3)*2
  {
    int r = lane >> 2, kp = (lane & 3) * 2;
    uint2 tv = *(const uint2*)&TS1H[((size_t)w * NN + i0 + r) * 8 + kp];
    s1h[r * 9 + kp] = tv.x;
    s1h[r * 9 + kp + 1] = tv.y;
  }
  // stage s2h buf0 for tile 0: lane -> j = lane
  {
    const u32* src = &TS2H[((size_t)w * NN + jch + lane) * 8];
    uint4 a = *(const uint4*)src;
    uint4 bq = *(const uint4*)(src + 4);
    u32* dst = s2h + lane * 9;
    dst[0] = a.x;  dst[1] = a.y;  dst[2] = a.z;  dst[3] = a.w;
    dst[4] = bq.x; dst[5] = bq.y; dst[6] = bq.z; dst[7] = bq.w;
  }
  const unsigned char* e8row = E8 + (size_t)(i0 + li) * NN;
  uint2 ea = *(const uint2*)(e8row + jch + q * 8);
  uint2 eb = *(const uint2*)(e8row + jch + 32 + q * 8);

  f32x4 acc[4];
#pragma unroll
  for (int n = 0; n < 4; ++n) acc[n] = (f32x4){0.f, 0.f, 0.f, 0.f};
  f32x4 acc_l = (f32x4){0.f, 0.f, 0.f, 0.f};
  const half8 ONE8 = {(_Float16)1.0f, (_Float16)1.0f, (_Float16)1.0f,
                      (_Float16)1.0f, (_Float16)1.0f, (_Float16)1.0f,
                      (_Float16)1.0f, (_Float16)1.0f};
  const _Float16 INV16 = (_Float16)0.0625f;

#pragma unroll 1
  for (int jt = 0; jt < 4; ++jt) {
    int jb = jch + jt * 64;
    int cur = jt & 1;

    // issue next tile's staging loads early (T14)
    uint4 nA = {0,0,0,0}, nB = {0,0,0,0};
    uint2 eaN = ea, ebN = eb;
    if (jt < 3) {
      const u32* src = &TS2H[((size_t)w * NN + jb + 64 + lane) * 8];
      nA = *(const uint4*)src;
      nB = *(const uint4*)(src + 4);
      eaN = *(const uint2*)(e8row + jb + 64 + q * 8);
      ebN = *(const uint2*)(e8row + jb + 96 + q * 8);
    }
    // bfrag loads for THIS tile (land under the score phase)
    half8 bfrag[4][2];
#pragma unroll
    for (int n = 0; n < 4; ++n)
#pragma unroll
      for (int s = 0; s < 2; ++s)
        bfrag[n][s] = *(const half8*)&VtH[(size_t)(w * 64 + n * 16 + li) * NN +
                                          jb + s * 32 + q * 8];

    // ---- scores: lane builds its own A-fragment elements
    const u32* s2c = s2h + cur * (64 * 9);
    half8 af0, af1;
#pragma unroll
    for (int s = 0; s < 2; ++s) {
#pragma unroll
      for (int e = 0; e < 8; ++e) {
        unsigned bx = (s == 0)
            ? ((e < 4) ? (ea.x >> (8 * e)) : (ea.y >> (8 * (e - 4))))
            : ((e < 4) ? (eb.x >> (8 * e)) : (eb.y >> (8 * (e - 4))));
        unsigned bcode = bx & 0xffu;
        int k = (int)(bcode & 7u);
        u32 jv = s2c[(s * 32 + e) * 9 + q * 72 + k];
        u32 iv = s1h[li * 9 + k];
        half2v pr = __builtin_bit_cast(half2v, iv) * __builtin_bit_cast(half2v, jv);
        _Float16 p = pr.x > pr.y ? pr.x : pr.y;
        p = (bcode & 8u) ? INV16 : p;
        if (s == 0) af0[e] = p; else af1[e] = p;
      }
    }

    // write next tile's s2 slice into the other buffer (wave-local ordering)
    if (jt < 3) {
      u32* dst = s2h + (cur ^ 1) * (64 * 9) + lane * 9;
      dst[0] = nA.x; dst[1] = nA.y; dst[2] = nA.z; dst[3] = nA.w;
      dst[4] = nB.x; dst[5] = nB.y; dst[6] = nB.z; dst[7] = nB.w;
    }

    // ---- MFMA cluster
    __builtin_amdgcn_s_setprio(1);
#pragma unroll
    for (int n = 0; n < 4; ++n) {
      acc[n] = __builtin_amdgcn_mfma_f32_16x16x32_f16(af0, bfrag[n][0], acc[n], 0, 0, 0);
      acc[n] = __builtin_amdgcn_mfma_f32_16x16x32_f16(af1, bfrag[n][1], acc[n], 0, 0, 0);
    }
    acc_l = __builtin_amdgcn_mfma_f32_16x16x32_f16(af0, ONE8, acc_l, 0, 0, 0);
    acc_l = __builtin_amdgcn_mfma_f32_16x16x32_f16(af1, ONE8, acc_l, 0, 0, 0);
    __builtin_amdgcn_s_setprio(0);

    ea = eaN; eb = ebN;
  }

  // denominator rows: D[q*4+r][*] all equal
  if (li == 0) {
#pragma unroll
    for (int r = 0; r < 4; ++r)
      LPART[((size_t)ch * NN + i0 + q * 4 + r) * 8 + w] = acc_l[r];
  }
  // partial numerators. C layout: col = lane&15, row = (lane>>4)*4 + reg
  float* base = PART + (size_t)ch * NN * DD;
#pragma unroll
  for (int n = 0; n < 4; ++n) {
#pragma unroll
    for (int r = 0; r < 4; ++r) {
      int row = i0 + q * 4 + r;
      int col = w * 64 + n * 16 + li;
      base[(size_t)row * DD + col] = acc[n][r];
    }
  }
}

// ---------------------------------------------------------------------------
// Kernel 4: combine 8 j-chunk partials, divide, project. grid 512, block 256.
// ---------------------------------------------------------------------------
__global__ __launch_bounds__(256) void proj_kernel(
    const float* __restrict__ PART, const float* __restrict__ LPART,
    const float* __restrict__ Pw, const float* __restrict__ Pb,
    float* __restrict__ out) {
  __shared__ __align__(16) float preS[4][512];
  __shared__ float linv[4][8];
  int t = threadIdx.x;
  int r0 = blockIdx.x * 4;
  if (t < 32) {
    int i = t >> 3, h = t & 7;
    float s = 0.f;
#pragma unroll
    for (int c = 0; c < 8; ++c)
      s += LPART[(size_t)c * NN * 8 + (size_t)(r0 + i) * 8 + h];
    linv[i][h] = 1.0f / s;
  }
  __syncthreads();
  for (int idx = t; idx < 4 * 128; idx += 256) {
    int i = idx >> 7, hd = (idx & 127) * 4;
    float4 v = {0.f, 0.f, 0.f, 0.f};
#pragma unroll
    for (int c = 0; c < 8; ++c) {
      float4 p = *(const float4*)&PART[(size_t)c * NN * DD + (size_t)(r0 + i) * DD + hd];
      v.x += p.x; v.y += p.y; v.z += p.z; v.w += p.w;
    }
    float li2 = linv[i][hd >> 6];
    v.x *= li2; v.y *= li2; v.z *= li2; v.w *= li2;
    *(float4*)&preS[i][hd] = v;
  }
  __syncthreads();
  int c = t & 63, rq = t >> 6;
  float acc0 = Pb[c];
  for (int hq = 0; hq < 128; ++hq) {
    int hd = hq * 4;
    float4 p0 = *(const float4*)&preS[rq][hd];
    float w0 = Pw[(hd + 0) * 64 + c];
    float w1 = Pw[(hd + 1) * 64 + c];
    float w2 = Pw[(hd + 2) * 64 + c];
    float w3 = Pw[(hd + 3) * 64 + c];
    acc0 += p0.x * w0 + p0.y * w1 + p0.z * w2 + p0.w * w3;
  }
  out[(size_t)(r0 + rq) * 64 + c] = acc0;
}

// ---------------------------------------------------------------------------
extern "C" void kernel_launch(void* const* d_in, const int* in_sizes, int n_in,
                              void* d_out, int out_size, void* d_ws, size_t ws_size,
                              hipStream_t stream) {
  const float* X  = (const float*)d_in[0];
  const int*   E  = (const int*)d_in[1];
  const float* Qw = (const float*)d_in[2];
  const float* Qb = (const float*)d_in[3];
  const float* Kw = (const float*)d_in[4];
  const float* Kb = (const float*)d_in[5];
  const float* Vw = (const float*)d_in[6];
  const float* Vb = (const float*)d_in[7];
  const float* A  = (const float*)d_in[8];
  const float* Pw = (const float*)d_in[9];
  const float* Pb = (const float*)d_in[10];
  float* out = (float*)d_out;

  float* ws = (float*)d_ws;
  const size_t ND = (size_t)NN * DD;              // 1M floats
  float* Q     = ws;                              // [0, 1M)
  float* K     = ws + ND;                         // [1M, 2M)
  float* PART  = ws;                              // [0, 8M) (aliases Q/K, dead)
  u32*   TS1H  = (u32*)(ws + 8 * ND);             // 512 KB
  u32*   TS2H  = TS1H + (size_t)NN * 64;          // 512 KB
  u16*   VtH   = (u16*)(TS2H + (size_t)NN * 64);  // 2 MB
  unsigned char* E8 = (unsigned char*)(VtH + (size_t)DD * NN);  // 4 MB
  float* LPART = (float*)(E8 + (size_t)NN * NN);  // 512 KB

  qkv_kernel<<<384, 256, 0, stream>>>(X, Qw, Qb, Kw, Kb, Vw, Vb, E, E8, Q, K, VtH);
  s12_kernel<<<512, 256, 0, stream>>>(Q, K, A, TS1H, TS2H);
  attn_mfma_kernel<<<1024, 512, 0, stream>>>(E8, TS1H, TS2H, VtH, PART, LPART);
  proj_kernel<<<512, 256, 0, stream>>>(PART, LPART, Pw, Pb, out);
}